// Round 3
// baseline (13763.815 us; speedup 1.0000x reference)
//
#include <hip/hip_runtime.h>
#include <hip/hip_fp16.h>

// ---------------------------------------------------------------------------
// 2-layer bidirectional tanh RNN, B=32, T=512, E=256, H=512.
//   prep:  fp32->fp16 conversions (+ xs transpose, bias sums)
//   gemm:  pre[d][t*32+b][j] = X @ W_ih[d]^T + bias   (fp16 MFMA)
//   rnn:   512 sequential steps; 16 blocks/dir, each owns a 32-wide j-slice
//          of W_hh in VGPRs. h exchanged via SELF-TAGGED u64 words
//          (tag<<32 | 2xfp16) with relaxed agent-scope atomics -> no fences,
//          no barriers, no L2 writeback/invalidate in the step loop.
// ---------------------------------------------------------------------------

#define T_ 512
#define B_ 32
#define E_ 256
#define H_ 512

using half8 = _Float16 __attribute__((ext_vector_type(8)));
using f32x4 = float __attribute__((ext_vector_type(4)));
typedef unsigned long long u64;

// workspace layout (bytes)
static constexpr size_t OFF_PRE   = 0;                         // f16 [2][16384][512]  32 MB
static constexpr size_t OFF_XH1   = 32ull << 20;               // f16 [16384][1024]    32 MB
static constexpr size_t OFF_X0H   = 64ull << 20;               // f16 [16384][256]      8 MB
static constexpr size_t OFF_W0H   = 72ull << 20;               // f16 [2][512][256]   0.5 MB
static constexpr size_t OFF_W1H   = OFF_W0H + (512ull << 10);  // f16 [2][512][1024]    2 MB
static constexpr size_t OFF_WHH   = OFF_W1H + (2ull << 20);    // f16 [2][2][512][512]  2 MB
static constexpr size_t OFF_BS    = OFF_WHH + (2ull << 20);    // f32 [2][2][512]       8 KB
static constexpr size_t OFF_HX    = OFF_BS + (8ull << 10);     // u64 [2 layer][2 dir][2 phase][32][256] 512 KB
static constexpr size_t ZERO_SIZE = 512ull << 10;

// ---------------------------------------------------------------------------
__global__ void prep_kernel(const float* __restrict__ xs,
                            const float* __restrict__ wih0,
                            const float* __restrict__ whh0,
                            const float* __restrict__ b0,
                            const float* __restrict__ wih1,
                            const float* __restrict__ whh1,
                            const float* __restrict__ b1,
                            _Float16* __restrict__ x0h,
                            _Float16* __restrict__ w0h,
                            _Float16* __restrict__ w1h,
                            _Float16* __restrict__ whh,
                            float* __restrict__ bsum)
{
    const int N0 = T_ * B_ * E_;
    const int N1 = 2 * H_ * E_;
    const int N2 = 2 * H_ * 2*H_;
    const int N3 = 2 * H_ * H_;
    const int total = N0 + N1 + N2 + 2 * N3 + 2048;
    for (int idx = blockIdx.x * blockDim.x + threadIdx.x; idx < total;
         idx += gridDim.x * blockDim.x) {
        int i = idx;
        if (i < N0) {
            int t = i >> 13;
            int r = i & 8191;
            int b = r >> 8;
            int e = r & 255;
            x0h[i] = (_Float16)xs[((size_t)(b << 9) + t) * 256 + e];
        } else if ((i -= N0) < N1) {
            w0h[i] = (_Float16)wih0[i];
        } else if ((i -= N1) < N2) {
            w1h[i] = (_Float16)wih1[i];
        } else if ((i -= N2) < N3) {
            whh[i] = (_Float16)whh0[i];
        } else if ((i -= N3) < N3) {
            whh[N3 + i] = (_Float16)whh1[i];
        } else {
            i -= N3;               // 0..2047: [layer][dir][512]
            int layer = i >> 10;
            int r = i & 1023;
            int d = r >> 9;
            int j = r & 511;
            const float* bb = layer ? b1 : b0;
            bsum[i] = bb[d * 1024 + j] + bb[d * 1024 + 512 + j];
        }
    }
}

// ---------------------------------------------------------------------------
__global__ __launch_bounds__(256, 2)
void gemm_kernel(const _Float16* __restrict__ X,
                 const _Float16* __restrict__ W,
                 const float* __restrict__ bias,
                 _Float16* __restrict__ out, int K)
{
    __shared__ _Float16 Ash[64][72];
    __shared__ _Float16 Bsh[64][72];
    const int m0 = blockIdx.x * 64, n0 = blockIdx.y * 64, d = blockIdx.z;
    const _Float16* Wd = W + (size_t)d * 512 * K;
    const int tid = threadIdx.x;
    const int l = tid & 63, w = tid >> 6;
    const int wm = w & 1, wn = w >> 1;
    const int lm = l & 15, q = l >> 4;
    f32x4 c[2][2] = {};
    for (int kk = 0; kk < K; kk += 64) {
        for (int ci = tid; ci < 512; ci += 256) {
            int row = ci >> 3, col = (ci & 7) * 8;
            *(half8*)&Ash[row][col] =
                *(const half8*)&X[(size_t)(m0 + row) * K + kk + col];
            *(half8*)&Bsh[row][col] =
                *(const half8*)&Wd[(size_t)(n0 + row) * K + kk + col];
        }
        __syncthreads();
        for (int kt = 0; kt < 2; ++kt) {
            const int kof = kt * 32 + q * 8;
            half8 a0 = *(const half8*)&Ash[wm * 32 + lm][kof];
            half8 a1 = *(const half8*)&Ash[wm * 32 + 16 + lm][kof];
            half8 b0f = *(const half8*)&Bsh[wn * 32 + lm][kof];
            half8 b1f = *(const half8*)&Bsh[wn * 32 + 16 + lm][kof];
            c[0][0] = __builtin_amdgcn_mfma_f32_16x16x32_f16(a0, b0f, c[0][0], 0, 0, 0);
            c[0][1] = __builtin_amdgcn_mfma_f32_16x16x32_f16(a0, b1f, c[0][1], 0, 0, 0);
            c[1][0] = __builtin_amdgcn_mfma_f32_16x16x32_f16(a1, b0f, c[1][0], 0, 0, 0);
            c[1][1] = __builtin_amdgcn_mfma_f32_16x16x32_f16(a1, b1f, c[1][1], 0, 0, 0);
        }
        __syncthreads();
    }
    _Float16* outd = out + (size_t)d * 16384 * 512;
    for (int mi = 0; mi < 2; ++mi)
        for (int ni = 0; ni < 2; ++ni) {
            int col = n0 + wn * 32 + ni * 16 + lm;
            float bv = bias[d * 512 + col];
            for (int r = 0; r < 4; ++r) {
                int rowm = m0 + wm * 32 + mi * 16 + q * 4 + r;
                outd[(size_t)rowm * 512 + col] = (_Float16)(c[mi][ni][r] + bv);
            }
        }
}

// ---------------------------------------------------------------------------
// hx words: [b=32][jpair=256], word = (tag << 32) | (fp16(j odd) << 16) | fp16(j even)
// h(s) lives in phase s&1 with tag s.  Writers at step s store tag s+1 into
// phase (s+1)&1.  Relaxed agent-scope atomics only — no fences, no flags.
__global__ __launch_bounds__(128, 1)
void rnn_kernel(const _Float16* __restrict__ pre,   // [2][16384][512] f16
                const _Float16* __restrict__ whh,   // this layer: [2][512][512] f16
                u64* __restrict__ hx,               // [2 dir][2 phase][32][256] u64
                _Float16* __restrict__ xh1,         // layer0 out: [16384][1024] f16
                float* __restrict__ dout,           // final output buffer
                int layer)
{
    const int gid = blockIdx.x;
    const int d = gid >> 4, g = gid & 15;
    const int tid = threadIdx.x, l = tid & 63, mt = tid >> 6;
    const int lm = l & 15, q = l >> 4;

    // Preload W B-fragments: lane holds W[j = n][k], n = lane&15, k = q*8+e.
    half8 Bf[2][16];
#pragma unroll
    for (int nt = 0; nt < 2; ++nt) {
        const _Float16* wrow = whh + ((size_t)d * 512 + g * 32 + nt * 16 + lm) * 512;
#pragma unroll
        for (int kt = 0; kt < 16; ++kt)
            Bf[nt][kt] = *(const half8*)&wrow[kt * 32 + q * 8];
    }

    const int bq = mt * 16 + q * 4;   // C/D row base (b), + reg r
    const int bA = mt * 16 + lm;      // A-fragment row (b)
    u64* hbd = hx + (size_t)d * 2 * 32 * 256;
    const int ntm = l & 1;            // which nt this lane publishes
    const int jp_pub = g * 16 + ntm * 8 + (lm >> 1);   // published jpair index

    for (int s = 0; s < T_; ++s) {
        const int t = d ? (T_ - 1 - s) : s;
        const u64* src = hbd + (size_t)(s & 1) * 32 * 256;
        u64* dst = hbd + (size_t)((s + 1) & 1) * 32 * 256;

        // ---- gather h(s) fragments: 64 tagged words per lane ----
        u64 wv[16][4];
        const u64* srow = src + (size_t)bA * 256 + q * 4;
#pragma unroll
        for (int kt = 0; kt < 16; ++kt)
#pragma unroll
            for (int i = 0; i < 4; ++i)
                wv[kt][i] = __hip_atomic_load(&srow[kt * 16 + i],
                                              __ATOMIC_RELAXED, __HIP_MEMORY_SCOPE_AGENT);
        const unsigned tag = (unsigned)s;
        {
            bool ok = false;
            while (!ok) {
                ok = true;
#pragma unroll
                for (int kt = 0; kt < 16; ++kt)
#pragma unroll
                    for (int i = 0; i < 4; ++i) {
                        if ((unsigned)(wv[kt][i] >> 32) != tag) {
                            wv[kt][i] = __hip_atomic_load(&srow[kt * 16 + i],
                                                          __ATOMIC_RELAXED, __HIP_MEMORY_SCOPE_AGENT);
                            if ((unsigned)(wv[kt][i] >> 32) != tag) ok = false;
                        }
                    }
            }
        }
        // unpack to A fragments
        half8 A[16];
#pragma unroll
        for (int kt = 0; kt < 16; ++kt) {
            union { unsigned u[4]; half8 h; } cv;
#pragma unroll
            for (int i = 0; i < 4; ++i) cv.u[i] = (unsigned)wv[kt][i];
            A[kt] = cv.h;
        }

        // ---- C init = pre[d][t][b][j] ----
        const _Float16* prow = pre + ((size_t)d * 16384 + (size_t)t * B_) * 512;
        f32x4 c[2];
#pragma unroll
        for (int nt = 0; nt < 2; ++nt) {
            const int j = g * 32 + nt * 16 + lm;
#pragma unroll
            for (int r = 0; r < 4; ++r)
                c[nt][r] = (float)prow[(size_t)(bq + r) * 512 + j];
        }

#pragma unroll
        for (int kt = 0; kt < 16; ++kt) {
            c[0] = __builtin_amdgcn_mfma_f32_16x16x32_f16(A[kt], Bf[0][kt], c[0], 0, 0, 0);
            c[1] = __builtin_amdgcn_mfma_f32_16x16x32_f16(A[kt], Bf[1][kt], c[1], 0, 0, 0);
        }

        // ---- tanh + outputs ----
        float hv_[2][4];
        unsigned hb_[2][4];
#pragma unroll
        for (int nt = 0; nt < 2; ++nt) {
            const int j = g * 32 + nt * 16 + lm;
#pragma unroll
            for (int r = 0; r < 4; ++r) {
                const float hv = tanhf(c[nt][r]);
                hv_[nt][r] = hv;
                union { _Float16 f; unsigned short u; } cb;
                cb.f = (_Float16)hv;
                hb_[nt][r] = cb.u;
                const int b = bq + r;
                if (layer == 0) {
                    xh1[((size_t)t * B_ + b) * 1024 + d * 512 + j] = (_Float16)hv;
                } else {
                    dout[((size_t)b * T_ + t) * 1024 + d * 512 + j] = hv;
                }
                if (s == T_ - 1) {
                    dout[16777216ull + ((size_t)(layer * 2 + d) * B_ + b) * 512 + j] = hv;
                }
            }
        }

        // ---- publish h(s+1): pair fp16 across adjacent lanes, tagged store ----
        const u64 tagw = ((u64)(unsigned)(s + 1)) << 32;
#pragma unroll
        for (int r = 0; r < 4; ++r) {
            unsigned p0 = __shfl_xor(hb_[0][r], 1, 64);
            unsigned p1 = __shfl_xor(hb_[1][r], 1, 64);
            unsigned lo, hi;
            if (!ntm) { lo = hb_[0][r]; hi = p0; }
            else      { lo = p1;        hi = hb_[1][r]; }
            u64 word = tagw | ((u64)hi << 16) | lo;
            __hip_atomic_store(&dst[(size_t)(bq + r) * 256 + jp_pub], word,
                               __ATOMIC_RELAXED, __HIP_MEMORY_SCOPE_AGENT);
        }
    }
}

// ---------------------------------------------------------------------------
extern "C" void kernel_launch(void* const* d_in, const int* in_sizes, int n_in,
                              void* d_out, int out_size, void* d_ws, size_t ws_size,
                              hipStream_t stream)
{
    const float* xs   = (const float*)d_in[0];
    const float* wih0 = (const float*)d_in[1];
    const float* whh0 = (const float*)d_in[2];
    const float* b0   = (const float*)d_in[3];
    const float* wih1 = (const float*)d_in[4];
    const float* whh1 = (const float*)d_in[5];
    const float* b1   = (const float*)d_in[6];

    char* ws = (char*)d_ws;
    _Float16* pre  = (_Float16*)(ws + OFF_PRE);
    _Float16* xh1  = (_Float16*)(ws + OFF_XH1);
    _Float16* x0h  = (_Float16*)(ws + OFF_X0H);
    _Float16* w0h  = (_Float16*)(ws + OFF_W0H);
    _Float16* w1h  = (_Float16*)(ws + OFF_W1H);
    _Float16* whh  = (_Float16*)(ws + OFF_WHH);
    float*    bsum = (float*)(ws + OFF_BS);
    u64*      hx   = (u64*)(ws + OFF_HX);
    float*    out  = (float*)d_out;

    // zero tagged h buffers (h(0)=0 with tag 0); ws is poisoned 0xAA
    (void)hipMemsetAsync(ws + OFF_HX, 0, ZERO_SIZE, stream);

    prep_kernel<<<2048, 256, 0, stream>>>(xs, wih0, whh0, b0, wih1, whh1, b1,
                                          x0h, w0h, w1h, whh, bsum);

    // layer 0
    gemm_kernel<<<dim3(256, 8, 2), 256, 0, stream>>>(x0h, w0h, bsum, pre, 256);
    rnn_kernel<<<32, 128, 0, stream>>>(pre, whh, hx, xh1, out, 0);

    // layer 1
    gemm_kernel<<<dim3(256, 8, 2), 256, 0, stream>>>(xh1, w1h, bsum + 1024, pre, 1024);
    rnn_kernel<<<32, 128, 0, stream>>>(pre, whh + 2 * 512 * 512,
                                       hx + 2 * 2 * 32 * 256, xh1, out, 1);
}

// Round 4
// 4348.508 us; speedup vs baseline: 3.1652x; 3.1652x over previous
//
#include <hip/hip_runtime.h>
#include <hip/hip_fp16.h>

// ---------------------------------------------------------------------------
// 2-layer bidirectional tanh RNN, B=32, T=512, E=256, H=512.
//   prep:  fp32->fp16 conversions (+ xs transpose, bias sums)
//   gemm:  pre[d][t*32+b][j] = X @ W_ih[d]^T + bias   (fp16 MFMA)
//   rnn:   512 sequential steps; 16 blocks/dir (256 thr), each owns a 32-wide
//          j-slice of W_hh in VGPRs. h exchanged as SELF-TAGGED u64 words
//          (tag<<32 | 2xfp16), relaxed agent-scope atomics (no fences, no
//          flags, no L2 maintenance). Reader loads the full tagged h with
//          COALESCED contiguous loads (512B/wave-instr), redistributes to
//          MFMA A-fragment layout via swizzled LDS.
// ---------------------------------------------------------------------------

#define T_ 512
#define B_ 32
#define E_ 256
#define H_ 512

using half8 = _Float16 __attribute__((ext_vector_type(8)));
using f32x4 = float __attribute__((ext_vector_type(4)));
typedef unsigned long long u64;
typedef unsigned int u32;

// workspace layout (bytes)
static constexpr size_t OFF_PRE   = 0;                         // f16 [2][16384][512]  32 MB
static constexpr size_t OFF_XH1   = 32ull << 20;               // f16 [16384][1024]    32 MB
static constexpr size_t OFF_X0H   = 64ull << 20;               // f16 [16384][256]      8 MB
static constexpr size_t OFF_W0H   = 72ull << 20;               // f16 [2][512][256]   0.5 MB
static constexpr size_t OFF_W1H   = OFF_W0H + (512ull << 10);  // f16 [2][512][1024]    2 MB
static constexpr size_t OFF_WHH   = OFF_W1H + (2ull << 20);    // f16 [2][2][512][512]  2 MB
static constexpr size_t OFF_BS    = OFF_WHH + (2ull << 20);    // f32 [2][2][512]       8 KB
static constexpr size_t OFF_HX    = OFF_BS + (8ull << 10);     // u64 [2 layer][2 dir][2 phase][32][256] 512 KB
static constexpr size_t ZERO_SIZE = 512ull << 10;

// ---------------------------------------------------------------------------
__global__ void prep_kernel(const float* __restrict__ xs,
                            const float* __restrict__ wih0,
                            const float* __restrict__ whh0,
                            const float* __restrict__ b0,
                            const float* __restrict__ wih1,
                            const float* __restrict__ whh1,
                            const float* __restrict__ b1,
                            _Float16* __restrict__ x0h,
                            _Float16* __restrict__ w0h,
                            _Float16* __restrict__ w1h,
                            _Float16* __restrict__ whh,
                            float* __restrict__ bsum)
{
    const int N0 = T_ * B_ * E_;
    const int N1 = 2 * H_ * E_;
    const int N2 = 2 * H_ * 2*H_;
    const int N3 = 2 * H_ * H_;
    const int total = N0 + N1 + N2 + 2 * N3 + 2048;
    for (int idx = blockIdx.x * blockDim.x + threadIdx.x; idx < total;
         idx += gridDim.x * blockDim.x) {
        int i = idx;
        if (i < N0) {
            int t = i >> 13;
            int r = i & 8191;
            int b = r >> 8;
            int e = r & 255;
            x0h[i] = (_Float16)xs[((size_t)(b << 9) + t) * 256 + e];
        } else if ((i -= N0) < N1) {
            w0h[i] = (_Float16)wih0[i];
        } else if ((i -= N1) < N2) {
            w1h[i] = (_Float16)wih1[i];
        } else if ((i -= N2) < N3) {
            whh[i] = (_Float16)whh0[i];
        } else if ((i -= N3) < N3) {
            whh[N3 + i] = (_Float16)whh1[i];
        } else {
            i -= N3;               // 0..2047: [layer][dir][512]
            int layer = i >> 10;
            int r = i & 1023;
            int d = r >> 9;
            int j = r & 511;
            const float* bb = layer ? b1 : b0;
            bsum[i] = bb[d * 1024 + j] + bb[d * 1024 + 512 + j];
        }
    }
}

// ---------------------------------------------------------------------------
__global__ __launch_bounds__(256, 2)
void gemm_kernel(const _Float16* __restrict__ X,
                 const _Float16* __restrict__ W,
                 const float* __restrict__ bias,
                 _Float16* __restrict__ out, int K)
{
    __shared__ _Float16 Ash[64][72];
    __shared__ _Float16 Bsh[64][72];
    const int m0 = blockIdx.x * 64, n0 = blockIdx.y * 64, d = blockIdx.z;
    const _Float16* Wd = W + (size_t)d * 512 * K;
    const int tid = threadIdx.x;
    const int l = tid & 63, w = tid >> 6;
    const int wm = w & 1, wn = w >> 1;
    const int lm = l & 15, q = l >> 4;
    f32x4 c[2][2] = {};
    for (int kk = 0; kk < K; kk += 64) {
        for (int ci = tid; ci < 512; ci += 256) {
            int row = ci >> 3, col = (ci & 7) * 8;
            *(half8*)&Ash[row][col] =
                *(const half8*)&X[(size_t)(m0 + row) * K + kk + col];
            *(half8*)&Bsh[row][col] =
                *(const half8*)&Wd[(size_t)(n0 + row) * K + kk + col];
        }
        __syncthreads();
        for (int kt = 0; kt < 2; ++kt) {
            const int kof = kt * 32 + q * 8;
            half8 a0 = *(const half8*)&Ash[wm * 32 + lm][kof];
            half8 a1 = *(const half8*)&Ash[wm * 32 + 16 + lm][kof];
            half8 b0f = *(const half8*)&Bsh[wn * 32 + lm][kof];
            half8 b1f = *(const half8*)&Bsh[wn * 32 + 16 + lm][kof];
            c[0][0] = __builtin_amdgcn_mfma_f32_16x16x32_f16(a0, b0f, c[0][0], 0, 0, 0);
            c[0][1] = __builtin_amdgcn_mfma_f32_16x16x32_f16(a0, b1f, c[0][1], 0, 0, 0);
            c[1][0] = __builtin_amdgcn_mfma_f32_16x16x32_f16(a1, b0f, c[1][0], 0, 0, 0);
            c[1][1] = __builtin_amdgcn_mfma_f32_16x16x32_f16(a1, b1f, c[1][1], 0, 0, 0);
        }
        __syncthreads();
    }
    _Float16* outd = out + (size_t)d * 16384 * 512;
    for (int mi = 0; mi < 2; ++mi)
        for (int ni = 0; ni < 2; ++ni) {
            int col = n0 + wn * 32 + ni * 16 + lm;
            float bv = bias[d * 512 + col];
            for (int r = 0; r < 4; ++r) {
                int rowm = m0 + wm * 32 + mi * 16 + q * 4 + r;
                outd[(size_t)rowm * 512 + col] = (_Float16)(c[mi][ni][r] + bv);
            }
        }
}

// ---------------------------------------------------------------------------
// hx per dir: [2 phase][32 b][256 jp] u64; word = (tag<<32)|(f16 j=2jp+1)<<16|(f16 j=2jp)
// h(s) lives in phase s&1 with tag s.  Block = 256 threads, 4 waves:
//   wave wv: wm = wv&1 (m-tile of b), wn = wv>>1 (16-col n-frag).
// Reader: 32 fully-coalesced u64 loads (load i, lane tid -> word [b=i][jp=tid]),
// tag-spin, then LDS scatter to A-frag layout [kg=64][b=32] half8 (pad 33).
__global__ __launch_bounds__(256)
void rnn_kernel(const _Float16* __restrict__ pre,   // [2][16384][512] f16
                const _Float16* __restrict__ whh,   // this layer: [2][512][512] f16
                u64* __restrict__ hx,               // [2 dir][2 phase][32][256] u64
                _Float16* __restrict__ xh1,         // layer0 out: [16384][1024] f16
                float* __restrict__ dout,           // final output buffer
                int layer)
{
    __shared__ uint4 As[64 * 33];                   // A-frag staging, 33.8 KB
    const int gid = blockIdx.x;
    const int d = gid >> 4, g = gid & 15;
    const int tid = threadIdx.x, wv = tid >> 6, l = tid & 63;
    const int lm = l & 15, q = l >> 4;
    const int wm = wv & 1, wn = wv >> 1;
    const int jn = g * 32 + wn * 16;                // this wave's 16-col slice
    const int bA = wm * 16 + lm;                    // A-frag row (b)
    const int bq = wm * 16 + q * 4;                 // C/D row base (b)

    // Preload W B-fragments: lane holds W[j = jn+lm][k = kt*32 + q*8 + e]
    half8 Bf[16];
    {
        const _Float16* wrow = whh + ((size_t)d * 512 + jn + lm) * 512;
#pragma unroll
        for (int kt = 0; kt < 16; ++kt)
            Bf[kt] = *(const half8*)&wrow[kt * 32 + q * 8];
    }

    u64* hbd = hx + (size_t)d * 2 * 8192;
    const int jp_pub = (jn + (lm & ~1)) >> 1;       // word this lane-pair publishes
    const int scat_base = ((tid >> 2) * 33) * 4 + (tid & 3);  // LDS dword idx base (b=0)
    u32* AsW = (u32*)As;

    for (int s = 0; s < T_; ++s) {
        const int t = d ? (T_ - 1 - s) : s;

        // ---- issue pre loads early (latency hides under the spin) ----
        const _Float16* prow = pre + ((size_t)d * 16384 + (size_t)t * B_) * 512 + jn + lm;
        float pv[4];
#pragma unroll
        for (int r = 0; r < 4; ++r)
            pv[r] = (float)prow[(size_t)(bq + r) * 512];

        // ---- coalesced tagged gather of full h(s): lane tid <- [b=i][jp=tid] ----
        const u64* src = hbd + (size_t)(s & 1) * 8192 + tid;
        u64 wvv[32];
#pragma unroll
        for (int i = 0; i < 32; ++i)
            wvv[i] = __hip_atomic_load(&src[i * 256],
                                       __ATOMIC_RELAXED, __HIP_MEMORY_SCOPE_AGENT);
        const unsigned tag = (unsigned)s;
        for (;;) {
            bool ok = true;
#pragma unroll
            for (int i = 0; i < 32; ++i)
                if ((unsigned)(wvv[i] >> 32) != tag) ok = false;
            if (ok) break;
#pragma unroll
            for (int i = 0; i < 32; ++i)
                if ((unsigned)(wvv[i] >> 32) != tag)
                    wvv[i] = __hip_atomic_load(&src[i * 256],
                                               __ATOMIC_RELAXED, __HIP_MEMORY_SCOPE_AGENT);
        }

        // ---- LDS scatter to A-frag layout (lane tid: kg=tid>>2, slot=tid&3) ----
        __syncthreads();   // previous step's frag reads done before overwrite
#pragma unroll
        for (int i = 0; i < 32; ++i)
            AsW[scat_base + i * 4] = (u32)wvv[i];
        __syncthreads();

        // ---- A-fragments + MFMA (two accumulators to halve dep chain) ----
        f32x4 c0, c1;
#pragma unroll
        for (int r = 0; r < 4; ++r) { c0[r] = pv[r]; c1[r] = 0.0f; }
#pragma unroll
        for (int kt = 0; kt < 16; ++kt) {
            union { uint4 u; half8 h; } cv;
            cv.u = As[(kt * 4 + q) * 33 + bA];
            if (kt & 1) c1 = __builtin_amdgcn_mfma_f32_16x16x32_f16(cv.h, Bf[kt], c1, 0, 0, 0);
            else        c0 = __builtin_amdgcn_mfma_f32_16x16x32_f16(cv.h, Bf[kt], c0, 0, 0, 0);
        }

        // ---- tanh + publish + outputs ----
        u64* dst = hbd + (size_t)((s + 1) & 1) * 8192;
        const u64 tagw = ((u64)(unsigned)(s + 1)) << 32;
        const int j = jn + lm;
        float hv[4];
        unsigned hb[4];
#pragma unroll
        for (int r = 0; r < 4; ++r) {
            hv[r] = tanhf(c0[r] + c1[r]);
            union { _Float16 f; unsigned short u; } cb;
            cb.f = (_Float16)hv[r];
            hb[r] = cb.u;
        }
#pragma unroll
        for (int r = 0; r < 4; ++r) {
            unsigned p = __shfl_xor(hb[r], 1, 64);
            unsigned lo = (l & 1) ? p : hb[r];
            unsigned hi = (l & 1) ? hb[r] : p;
            if ((r >> 1) == (l & 1)) {   // even lane stores r=0,1; odd r=2,3
                u64 word = tagw | ((u64)hi << 16) | lo;
                __hip_atomic_store(&dst[(size_t)(bq + r) * 256 + jp_pub], word,
                                   __ATOMIC_RELAXED, __HIP_MEMORY_SCOPE_AGENT);
            }
        }
#pragma unroll
        for (int r = 0; r < 4; ++r) {
            const int b = bq + r;
            if (layer == 0) {
                xh1[((size_t)t * B_ + b) * 1024 + d * 512 + j] = (_Float16)hv[r];
            } else {
                dout[((size_t)b * T_ + t) * 1024 + d * 512 + j] = hv[r];
            }
            if (s == T_ - 1) {
                dout[16777216ull + ((size_t)(layer * 2 + d) * B_ + b) * 512 + j] = hv[r];
            }
        }
    }
}

// ---------------------------------------------------------------------------
extern "C" void kernel_launch(void* const* d_in, const int* in_sizes, int n_in,
                              void* d_out, int out_size, void* d_ws, size_t ws_size,
                              hipStream_t stream)
{
    const float* xs   = (const float*)d_in[0];
    const float* wih0 = (const float*)d_in[1];
    const float* whh0 = (const float*)d_in[2];
    const float* b0   = (const float*)d_in[3];
    const float* wih1 = (const float*)d_in[4];
    const float* whh1 = (const float*)d_in[5];
    const float* b1   = (const float*)d_in[6];

    char* ws = (char*)d_ws;
    _Float16* pre  = (_Float16*)(ws + OFF_PRE);
    _Float16* xh1  = (_Float16*)(ws + OFF_XH1);
    _Float16* x0h  = (_Float16*)(ws + OFF_X0H);
    _Float16* w0h  = (_Float16*)(ws + OFF_W0H);
    _Float16* w1h  = (_Float16*)(ws + OFF_W1H);
    _Float16* whh  = (_Float16*)(ws + OFF_WHH);
    float*    bsum = (float*)(ws + OFF_BS);
    u64*      hx   = (u64*)(ws + OFF_HX);
    float*    out  = (float*)d_out;

    // zero tagged h buffers (h(0)=0 with tag 0); ws is poisoned 0xAA
    (void)hipMemsetAsync(ws + OFF_HX, 0, ZERO_SIZE, stream);

    prep_kernel<<<2048, 256, 0, stream>>>(xs, wih0, whh0, b0, wih1, whh1, b1,
                                          x0h, w0h, w1h, whh, bsum);

    // layer 0
    gemm_kernel<<<dim3(256, 8, 2), 256, 0, stream>>>(x0h, w0h, bsum, pre, 256);
    rnn_kernel<<<32, 256, 0, stream>>>(pre, whh, hx, xh1, out, 0);

    // layer 1
    gemm_kernel<<<dim3(256, 8, 2), 256, 0, stream>>>(xh1, w1h, bsum + 1024, pre, 1024);
    rnn_kernel<<<32, 256, 0, stream>>>(pre, whh + 2 * 512 * 512,
                                       hx + 2 * 2 * 8192, xh1, out, 1);
}

// Round 5
// 2894.293 us; speedup vs baseline: 4.7555x; 1.5024x over previous
//
#include <hip/hip_runtime.h>
#include <hip/hip_fp16.h>

// ---------------------------------------------------------------------------
// 2-layer bidirectional tanh RNN, B=32, T=512, E=256, H=512.
//   prep:  fp32->fp16 conversions (+ xs transpose, bias sums)
//   gemm:  pre[d][t*32+b][j] = X @ W_ih[d]^T + bias   (fp16 MFMA)
//   rnn:   512 sequential steps; 16 blocks/dir (256 thr), each owns a 32-wide
//          j-slice of W_hh in VGPRs. h exchanged as SELF-TAGGED u64 words
//          (tag<<32 | 2xfp16) via SYSTEM-scope relaxed atomics: sc0+sc1 ->
//          bypass L1+L2, served by LLC. (Agent scope read stale per-XCD L2 —
//          round-4 lesson: 4.2us/step eviction-churn stalls.)  No fences, no
//          flags, no cache-maintenance ops anywhere in the step loop.
// ---------------------------------------------------------------------------

#define T_ 512
#define B_ 32
#define E_ 256
#define H_ 512

using half8 = _Float16 __attribute__((ext_vector_type(8)));
using f32x4 = float __attribute__((ext_vector_type(4)));
typedef unsigned long long u64;
typedef unsigned int u32;

// workspace layout (bytes)
static constexpr size_t OFF_PRE   = 0;                         // f16 [2][16384][512]  32 MB
static constexpr size_t OFF_XH1   = 32ull << 20;               // f16 [16384][1024]    32 MB
static constexpr size_t OFF_X0H   = 64ull << 20;               // f16 [16384][256]      8 MB
static constexpr size_t OFF_W0H   = 72ull << 20;               // f16 [2][512][256]   0.5 MB
static constexpr size_t OFF_W1H   = OFF_W0H + (512ull << 10);  // f16 [2][512][1024]    2 MB
static constexpr size_t OFF_WHH   = OFF_W1H + (2ull << 20);    // f16 [2][2][512][512]  2 MB
static constexpr size_t OFF_BS    = OFF_WHH + (2ull << 20);    // f32 [2][2][512]       8 KB
static constexpr size_t OFF_HX    = OFF_BS + (8ull << 10);     // u64 [2 layer][2 dir][2 phase][32][256] 512 KB
static constexpr size_t ZERO_SIZE = 512ull << 10;

__device__ __forceinline__ float fast_tanh(float x) {
    // tanh(x) = (e^2x - 1)/(e^2x + 1), clamped so e^2x can't overflow.
    float cx = fminf(fmaxf(x, -9.0f), 9.0f);
    float e2 = __expf(2.0f * cx);
    return (e2 - 1.0f) * __builtin_amdgcn_rcpf(e2 + 1.0f);
}

// ---------------------------------------------------------------------------
__global__ void prep_kernel(const float* __restrict__ xs,
                            const float* __restrict__ wih0,
                            const float* __restrict__ whh0,
                            const float* __restrict__ b0,
                            const float* __restrict__ wih1,
                            const float* __restrict__ whh1,
                            const float* __restrict__ b1,
                            _Float16* __restrict__ x0h,
                            _Float16* __restrict__ w0h,
                            _Float16* __restrict__ w1h,
                            _Float16* __restrict__ whh,
                            float* __restrict__ bsum)
{
    const int N0 = T_ * B_ * E_;
    const int N1 = 2 * H_ * E_;
    const int N2 = 2 * H_ * 2*H_;
    const int N3 = 2 * H_ * H_;
    const int total = N0 + N1 + N2 + 2 * N3 + 2048;
    for (int idx = blockIdx.x * blockDim.x + threadIdx.x; idx < total;
         idx += gridDim.x * blockDim.x) {
        int i = idx;
        if (i < N0) {
            int t = i >> 13;
            int r = i & 8191;
            int b = r >> 8;
            int e = r & 255;
            x0h[i] = (_Float16)xs[((size_t)(b << 9) + t) * 256 + e];
        } else if ((i -= N0) < N1) {
            w0h[i] = (_Float16)wih0[i];
        } else if ((i -= N1) < N2) {
            w1h[i] = (_Float16)wih1[i];
        } else if ((i -= N2) < N3) {
            whh[i] = (_Float16)whh0[i];
        } else if ((i -= N3) < N3) {
            whh[N3 + i] = (_Float16)whh1[i];
        } else {
            i -= N3;               // 0..2047: [layer][dir][512]
            int layer = i >> 10;
            int r = i & 1023;
            int d = r >> 9;
            int j = r & 511;
            const float* bb = layer ? b1 : b0;
            bsum[i] = bb[d * 1024 + j] + bb[d * 1024 + 512 + j];
        }
    }
}

// ---------------------------------------------------------------------------
__global__ __launch_bounds__(256, 2)
void gemm_kernel(const _Float16* __restrict__ X,
                 const _Float16* __restrict__ W,
                 const float* __restrict__ bias,
                 _Float16* __restrict__ out, int K)
{
    __shared__ _Float16 Ash[64][72];
    __shared__ _Float16 Bsh[64][72];
    const int m0 = blockIdx.x * 64, n0 = blockIdx.y * 64, d = blockIdx.z;
    const _Float16* Wd = W + (size_t)d * 512 * K;
    const int tid = threadIdx.x;
    const int l = tid & 63, w = tid >> 6;
    const int wm = w & 1, wn = w >> 1;
    const int lm = l & 15, q = l >> 4;
    f32x4 c[2][2] = {};
    for (int kk = 0; kk < K; kk += 64) {
        for (int ci = tid; ci < 512; ci += 256) {
            int row = ci >> 3, col = (ci & 7) * 8;
            *(half8*)&Ash[row][col] =
                *(const half8*)&X[(size_t)(m0 + row) * K + kk + col];
            *(half8*)&Bsh[row][col] =
                *(const half8*)&Wd[(size_t)(n0 + row) * K + kk + col];
        }
        __syncthreads();
        for (int kt = 0; kt < 2; ++kt) {
            const int kof = kt * 32 + q * 8;
            half8 a0 = *(const half8*)&Ash[wm * 32 + lm][kof];
            half8 a1 = *(const half8*)&Ash[wm * 32 + 16 + lm][kof];
            half8 b0f = *(const half8*)&Bsh[wn * 32 + lm][kof];
            half8 b1f = *(const half8*)&Bsh[wn * 32 + 16 + lm][kof];
            c[0][0] = __builtin_amdgcn_mfma_f32_16x16x32_f16(a0, b0f, c[0][0], 0, 0, 0);
            c[0][1] = __builtin_amdgcn_mfma_f32_16x16x32_f16(a0, b1f, c[0][1], 0, 0, 0);
            c[1][0] = __builtin_amdgcn_mfma_f32_16x16x32_f16(a1, b0f, c[1][0], 0, 0, 0);
            c[1][1] = __builtin_amdgcn_mfma_f32_16x16x32_f16(a1, b1f, c[1][1], 0, 0, 0);
        }
        __syncthreads();
    }
    _Float16* outd = out + (size_t)d * 16384 * 512;
    for (int mi = 0; mi < 2; ++mi)
        for (int ni = 0; ni < 2; ++ni) {
            int col = n0 + wn * 32 + ni * 16 + lm;
            float bv = bias[d * 512 + col];
            for (int r = 0; r < 4; ++r) {
                int rowm = m0 + wm * 32 + mi * 16 + q * 4 + r;
                outd[(size_t)rowm * 512 + col] = (_Float16)(c[mi][ni][r] + bv);
            }
        }
}

// ---------------------------------------------------------------------------
// hx per dir: [2 phase][32 b][256 jp] u64; word = (tag<<32)|(f16 j=2jp+1)<<16|(f16 j=2jp)
// h(s) lives in phase s&1 with tag s.  Block = 256 threads, 4 waves:
//   wave wv: wm = wv&1 (m-tile of b), wn = wv>>1 (16-col n-frag).
// Reader: 32 fully-coalesced u64 SYSTEM-scope loads (lane tid -> [b=i][jp=tid]),
// wave-uniform batched tag-spin, then LDS scatter to A-frag layout.
__global__ __launch_bounds__(256)
void rnn_kernel(const _Float16* __restrict__ pre,   // [2][16384][512] f16
                const _Float16* __restrict__ whh,   // this layer: [2][512][512] f16
                u64* __restrict__ hx,               // [2 dir][2 phase][32][256] u64
                _Float16* __restrict__ xh1,         // layer0 out: [16384][1024] f16
                float* __restrict__ dout,           // final output buffer
                int layer)
{
    __shared__ uint4 As[64 * 33];                   // A-frag staging, 33.8 KB
    const int gid = blockIdx.x;
    const int d = gid >> 4, g = gid & 15;
    const int tid = threadIdx.x, wv = tid >> 6, l = tid & 63;
    const int lm = l & 15, q = l >> 4;
    const int wm = wv & 1, wn = wv >> 1;
    const int jn = g * 32 + wn * 16;                // this wave's 16-col slice
    const int bA = wm * 16 + lm;                    // A-frag row (b)
    const int bq = wm * 16 + q * 4;                 // C/D row base (b)

    // Preload W B-fragments: lane holds W[j = jn+lm][k = kt*32 + q*8 + e]
    half8 Bf[16];
    {
        const _Float16* wrow = whh + ((size_t)d * 512 + jn + lm) * 512;
#pragma unroll
        for (int kt = 0; kt < 16; ++kt)
            Bf[kt] = *(const half8*)&wrow[kt * 32 + q * 8];
    }

    u64* hbd = hx + (size_t)d * 2 * 8192;
    const int jp_pub = (jn + (lm & ~1)) >> 1;       // word this lane-pair publishes
    const int scat_base = ((tid >> 2) * 33) * 4 + (tid & 3);  // LDS dword idx base (b=0)
    u32* AsW = (u32*)As;

    for (int s = 0; s < T_; ++s) {
        const int t = d ? (T_ - 1 - s) : s;

        // ---- issue pre loads early (latency hides under the spin) ----
        const _Float16* prow = pre + ((size_t)d * 16384 + (size_t)t * B_) * 512 + jn + lm;
        _Float16 pv[4];
#pragma unroll
        for (int r = 0; r < 4; ++r)
            pv[r] = prow[(size_t)(bq + r) * 512];

        // ---- coalesced tagged gather of full h(s): lane tid <- [b=i][jp=tid] ----
        // SYSTEM scope => sc0 sc1 => bypass (stale) L1/L2, read LLC.
        const u64* src = hbd + (size_t)(s & 1) * 8192 + tid;
        const unsigned tag = (unsigned)s;
        u64 wvv[32];
        bool stale = true;
        do {
#pragma unroll
            for (int i = 0; i < 32; ++i)
                wvv[i] = __hip_atomic_load(&src[i * 256],
                                           __ATOMIC_RELAXED, __HIP_MEMORY_SCOPE_SYSTEM);
            bool ok = true;
#pragma unroll
            for (int i = 0; i < 32; ++i)
                ok &= ((unsigned)(wvv[i] >> 32) == tag);
            stale = __any(!ok);
        } while (stale);

        // ---- LDS scatter to A-frag layout (lane tid: kg=tid>>2, slot=tid&3) ----
        __syncthreads();   // previous step's frag reads done before overwrite
#pragma unroll
        for (int i = 0; i < 32; ++i)
            AsW[scat_base + i * 4] = (u32)wvv[i];
        __syncthreads();

        // ---- A-fragments + MFMA (two accumulators to halve dep chain) ----
        f32x4 c0, c1;
#pragma unroll
        for (int r = 0; r < 4; ++r) { c0[r] = (float)pv[r]; c1[r] = 0.0f; }
#pragma unroll
        for (int kt = 0; kt < 16; ++kt) {
            union { uint4 u; half8 h; } cv;
            cv.u = As[(kt * 4 + q) * 33 + bA];
            if (kt & 1) c1 = __builtin_amdgcn_mfma_f32_16x16x32_f16(cv.h, Bf[kt], c1, 0, 0, 0);
            else        c0 = __builtin_amdgcn_mfma_f32_16x16x32_f16(cv.h, Bf[kt], c0, 0, 0, 0);
        }

        // ---- tanh + publish + outputs ----
        u64* dst = hbd + (size_t)((s + 1) & 1) * 8192;
        const u64 tagw = ((u64)(unsigned)(s + 1)) << 32;
        const int j = jn + lm;
        float hv[4];
        unsigned hb[4];
#pragma unroll
        for (int r = 0; r < 4; ++r) {
            hv[r] = fast_tanh(c0[r] + c1[r]);
            union { _Float16 f; unsigned short u; } cb;
            cb.f = (_Float16)hv[r];
            hb[r] = cb.u;
        }
#pragma unroll
        for (int r = 0; r < 4; ++r) {
            unsigned p = __shfl_xor(hb[r], 1, 64);
            unsigned lo = (l & 1) ? p : hb[r];
            unsigned hi = (l & 1) ? hb[r] : p;
            if ((r >> 1) == (l & 1)) {   // even lane stores r=0,1; odd r=2,3
                u64 word = tagw | ((u64)hi << 16) | lo;
                __hip_atomic_store(&dst[(size_t)(bq + r) * 256 + jp_pub], word,
                                   __ATOMIC_RELAXED, __HIP_MEMORY_SCOPE_SYSTEM);
            }
        }
#pragma unroll
        for (int r = 0; r < 4; ++r) {
            const int b = bq + r;
            if (layer == 0) {
                xh1[((size_t)t * B_ + b) * 1024 + d * 512 + j] = (_Float16)hv[r];
            } else {
                dout[((size_t)b * T_ + t) * 1024 + d * 512 + j] = hv[r];
            }
            if (s == T_ - 1) {
                dout[16777216ull + ((size_t)(layer * 2 + d) * B_ + b) * 512 + j] = hv[r];
            }
        }
    }
}

// ---------------------------------------------------------------------------
extern "C" void kernel_launch(void* const* d_in, const int* in_sizes, int n_in,
                              void* d_out, int out_size, void* d_ws, size_t ws_size,
                              hipStream_t stream)
{
    const float* xs   = (const float*)d_in[0];
    const float* wih0 = (const float*)d_in[1];
    const float* whh0 = (const float*)d_in[2];
    const float* b0   = (const float*)d_in[3];
    const float* wih1 = (const float*)d_in[4];
    const float* whh1 = (const float*)d_in[5];
    const float* b1   = (const float*)d_in[6];

    char* ws = (char*)d_ws;
    _Float16* pre  = (_Float16*)(ws + OFF_PRE);
    _Float16* xh1  = (_Float16*)(ws + OFF_XH1);
    _Float16* x0h  = (_Float16*)(ws + OFF_X0H);
    _Float16* w0h  = (_Float16*)(ws + OFF_W0H);
    _Float16* w1h  = (_Float16*)(ws + OFF_W1H);
    _Float16* whh  = (_Float16*)(ws + OFF_WHH);
    float*    bsum = (float*)(ws + OFF_BS);
    u64*      hx   = (u64*)(ws + OFF_HX);
    float*    out  = (float*)d_out;

    // zero tagged h buffers (h(0)=0 with tag 0); ws is poisoned 0xAA
    (void)hipMemsetAsync(ws + OFF_HX, 0, ZERO_SIZE, stream);

    prep_kernel<<<2048, 256, 0, stream>>>(xs, wih0, whh0, b0, wih1, whh1, b1,
                                          x0h, w0h, w1h, whh, bsum);

    // layer 0
    gemm_kernel<<<dim3(256, 8, 2), 256, 0, stream>>>(x0h, w0h, bsum, pre, 256);
    rnn_kernel<<<32, 256, 0, stream>>>(pre, whh, hx, xh1, out, 0);

    // layer 1
    gemm_kernel<<<dim3(256, 8, 2), 256, 0, stream>>>(xh1, w1h, bsum + 1024, pre, 1024);
    rnn_kernel<<<32, 256, 0, stream>>>(pre, whh + 2 * 512 * 512,
                                       hx + 2 * 2 * 8192, xh1, out, 1);
}